// Round 1
// baseline (336.437 us; speedup 1.0000x reference)
//
#include <hip/hip_runtime.h>
#include <math.h>

#define NBATCH 128
#define NP 256
#define NC 64
#define KNN 16
#define EPSV 1e-3f

#define KSTR 20                   // floats per c-row in LDS slab (pad for bank spread)
#define PSTR (NC * KSTR + 4)      // floats per point slab (1284) — +4 staggers groups across banks

// ---------------------------------------------------------------------------
// kNN: one block per batch, one thread per query point. f64 distances so the
// ordering equals the true ordering (reference formula r - 2m + r^T is exact-
// equivalent in f64 at f32 inputs; self-distance is exactly 0 = unique min).
// ---------------------------------------------------------------------------
__global__ __launch_bounds__(256) void knn_kernel(const float* __restrict__ points,
                                                  int* __restrict__ idx_out) {
    const int b = blockIdx.x;
    const int t = threadIdx.x;
    __shared__ double sx[NP], sy[NP], sz[NP], sr[NP];
    const float* pb = points + (size_t)b * NP * 3;
    {
        double x = (double)pb[t * 3 + 0];
        double y = (double)pb[t * 3 + 1];
        double z = (double)pb[t * 3 + 2];
        sx[t] = x; sy[t] = y; sz[t] = z;
        sr[t] = x * x + y * y + z * z;
    }
    __syncthreads();
    const double qx = sx[t], qy = sy[t], qz = sz[t], rp = sr[t];

    double bd[KNN];
    int bi[KNN];
#pragma unroll
    for (int i = 0; i < KNN; ++i) { bd[i] = 1e300; bi[i] = 0; }

    for (int q = 0; q < NP; ++q) {
        if (q == t) continue;
        double m = qx * sx[q] + qy * sy[q] + qz * sz[q];
        double d = (rp - 2.0 * m) + sr[q];
        if (d < bd[KNN - 1]) {
            // predicated insertion into sorted-ascending list (static indices only)
#pragma unroll
            for (int i = KNN - 1; i >= 1; --i) {
                const bool wr = d < bd[i];
                const bool sh = d < bd[i - 1];
                const double nd = sh ? bd[i - 1] : d;
                const int   ni = sh ? bi[i - 1] : q;
                if (wr) { bd[i] = nd; bi[i] = ni; }
            }
            if (d < bd[0]) { bd[0] = d; bi[0] = q; }
        }
    }
    int* op = idx_out + ((size_t)b * NP + t) * KNN;
#pragma unroll
    for (int i = 0; i < KNN; ++i) op[i] = bi[i];
}

// ---------------------------------------------------------------------------
// Edge MLP. One wave (64 threads) per block, 4 points per wave.
// lane = (g = point 0..3, cc = channel-quad 0..15); lane owns channels 4cc..4cc+3
// and all 16 k-rows => acc[16][4] in registers, 64 FMA per ds_read_b128 quad.
// Activations live in one in-place LDS slab per point (rows = c, cols = k).
// ---------------------------------------------------------------------------
__device__ __forceinline__ void mlp_layer(const float* __restrict__ xbase,
                                          const float* __restrict__ w,
                                          int d0, float acc[16][4]) {
#pragma unroll 2
    for (int c = 0; c < NC; ++c) {
        const float* xr = xbase + c * KSTR;
        float4 x0 = *(const float4*)(xr + 0);
        float4 x1 = *(const float4*)(xr + 4);
        float4 x2 = *(const float4*)(xr + 8);
        float4 x3 = *(const float4*)(xr + 12);
        float4 wv = *(const float4*)(w + c * NC + d0);
        const float xs[16] = {x0.x, x0.y, x0.z, x0.w, x1.x, x1.y, x1.z, x1.w,
                              x2.x, x2.y, x2.z, x2.w, x3.x, x3.y, x3.z, x3.w};
#pragma unroll
        for (int k = 0; k < 16; ++k) {
            acc[k][0] = fmaf(xs[k], wv.x, acc[k][0]);
            acc[k][1] = fmaf(xs[k], wv.y, acc[k][1]);
            acc[k][2] = fmaf(xs[k], wv.z, acc[k][2]);
            acc[k][3] = fmaf(xs[k], wv.w, acc[k][3]);
        }
    }
}

__device__ __forceinline__ void make_bn(const float* __restrict__ gamma,
                                        const float* __restrict__ beta,
                                        const float* __restrict__ mean,
                                        const float* __restrict__ var,
                                        int d0, float scl[4], float shf[4]) {
    float4 gg = *(const float4*)(gamma + d0);
    float4 bb = *(const float4*)(beta + d0);
    float4 mm = *(const float4*)(mean + d0);
    float4 vv = *(const float4*)(var + d0);
    const float* gp = (const float*)&gg;
    const float* bp = (const float*)&bb;
    const float* mp = (const float*)&mm;
    const float* vp = (const float*)&vv;
#pragma unroll
    for (int r = 0; r < 4; ++r) {
        scl[r] = gp[r] * rsqrtf(vp[r] + EPSV);
        shf[r] = fmaf(-mp[r], scl[r], bp[r]);
    }
}

__device__ __forceinline__ void bn_relu_store(float* __restrict__ xbase, int d0,
                                              const float scl[4], const float shf[4],
                                              float acc[16][4]) {
#pragma unroll
    for (int r = 0; r < 4; ++r) {
        float* dst = xbase + (d0 + r) * KSTR;
#pragma unroll
        for (int kq = 0; kq < 4; ++kq) {
            float4 v;
            v.x = fmaxf(fmaf(acc[kq * 4 + 0][r], scl[r], shf[r]), 0.f);
            v.y = fmaxf(fmaf(acc[kq * 4 + 1][r], scl[r], shf[r]), 0.f);
            v.z = fmaxf(fmaf(acc[kq * 4 + 2][r], scl[r], shf[r]), 0.f);
            v.w = fmaxf(fmaf(acc[kq * 4 + 3][r], scl[r], shf[r]), 0.f);
            *(float4*)(dst + kq * 4) = v;
        }
    }
}

__global__ __launch_bounds__(64) void edgeconv_kernel(
    const float* __restrict__ features,
    const float* __restrict__ w0,
    const float* __restrict__ w1,
    const float* __restrict__ w2,
    const float* __restrict__ gammas,
    const float* __restrict__ betas,
    const float* __restrict__ means,
    const float* __restrict__ variances,
    const float* __restrict__ sc_w,
    const float* __restrict__ sc_gamma,
    const float* __restrict__ sc_beta,
    const float* __restrict__ sc_mean,
    const float* __restrict__ sc_var,
    const int* __restrict__ knn_idx,
    float* __restrict__ out) {
    __shared__ __align__(16) float sNB[4 * PSTR];
    __shared__ __align__(16) float sCTR[4][NC];
    __shared__ int sIDX[64];

    const int blk = blockIdx.x;
    const int b = blk >> 6;
    const int p0 = (blk & 63) * 4;
    const int lane = threadIdx.x;
    const int g = lane >> 4;
    const int cc = lane & 15;
    const int d0 = cc * 4;

    const float* fb = features + (size_t)b * NP * NC;
    const size_t bp0 = (size_t)b * NP + p0;

    // center features (4 coalesced 256B rows)
#pragma unroll
    for (int jj = 0; jj < 4; ++jj)
        sCTR[jj][lane] = fb[(p0 + jj) * NC + lane];
    // neighbor indices: lane -> (g, k=cc)
    sIDX[lane] = knn_idx[(bp0 + g) * KNN + cc];
    __syncthreads();

    // gather: lane (g, k) reads its neighbor row, writes transposed [c][k]
    {
        const int row = sIDX[lane];
        const float* src = fb + (size_t)row * NC;
        float* dst = &sNB[g * PSTR + cc];
#pragma unroll
        for (int q = 0; q < 16; ++q) {
            float4 v = *(const float4*)(src + q * 4);
            dst[(q * 4 + 0) * KSTR] = v.x;
            dst[(q * 4 + 1) * KSTR] = v.y;
            dst[(q * 4 + 2) * KSTR] = v.z;
            dst[(q * 4 + 3) * KSTR] = v.w;
        }
    }
    __syncthreads();

    float* xbase = &sNB[g * PSTR];
    const float* ctr = &sCTR[g][0];

    // ---- layer 1: y1 = s0 + nbr @ w0_hi ----
    // s0[r] = sum_c ctr[c] * (w0[c][d] - w0[64+c][d])  (center term, k-invariant)
    float s0[4] = {0.f, 0.f, 0.f, 0.f};
#pragma unroll 4
    for (int c4 = 0; c4 < 16; ++c4) {
        float4 cv = *(const float4*)(ctr + c4 * 4);
        const float* cvp = (const float*)&cv;
#pragma unroll
        for (int u = 0; u < 4; ++u) {
            const int c = c4 * 4 + u;
            float4 wa = *(const float4*)(w0 + c * NC + d0);
            float4 wb = *(const float4*)(w0 + (NC + c) * NC + d0);
            s0[0] = fmaf(cvp[u], wa.x - wb.x, s0[0]);
            s0[1] = fmaf(cvp[u], wa.y - wb.y, s0[1]);
            s0[2] = fmaf(cvp[u], wa.z - wb.z, s0[2]);
            s0[3] = fmaf(cvp[u], wa.w - wb.w, s0[3]);
        }
    }

    float acc[16][4];
#pragma unroll
    for (int k = 0; k < 16; ++k) {
        acc[k][0] = s0[0]; acc[k][1] = s0[1]; acc[k][2] = s0[2]; acc[k][3] = s0[3];
    }
    mlp_layer(xbase, w0 + NC * NC, d0, acc);
    {
        float scl[4], shf[4];
        make_bn(gammas + 0 * NC, betas + 0 * NC, means + 0 * NC, variances + 0 * NC, d0, scl, shf);
        bn_relu_store(xbase, d0, scl, shf, acc);
    }
    __syncthreads();

    // ---- layer 2 ----
#pragma unroll
    for (int k = 0; k < 16; ++k) { acc[k][0] = 0.f; acc[k][1] = 0.f; acc[k][2] = 0.f; acc[k][3] = 0.f; }
    mlp_layer(xbase, w1, d0, acc);
    {
        float scl[4], shf[4];
        make_bn(gammas + 1 * NC, betas + 1 * NC, means + 1 * NC, variances + 1 * NC, d0, scl, shf);
        bn_relu_store(xbase, d0, scl, shf, acc);
    }
    __syncthreads();

    // ---- layer 3 (output stays in registers; mean over k) ----
#pragma unroll
    for (int k = 0; k < 16; ++k) { acc[k][0] = 0.f; acc[k][1] = 0.f; acc[k][2] = 0.f; acc[k][3] = 0.f; }
    mlp_layer(xbase, w2, d0, acc);

    float fts[4];
    {
        float scl[4], shf[4];
        make_bn(gammas + 2 * NC, betas + 2 * NC, means + 2 * NC, variances + 2 * NC, d0, scl, shf);
#pragma unroll
        for (int r = 0; r < 4; ++r) {
            float s = 0.f;
#pragma unroll
            for (int k = 0; k < 16; ++k)
                s += fmaxf(fmaf(acc[k][r], scl[r], shf[r]), 0.f);
            fts[r] = s * (1.f / 16.f);
        }
    }

    // ---- shortcut: sc = bn(ctr @ sc_w); out = relu(sc + fts) ----
    float sc[4] = {0.f, 0.f, 0.f, 0.f};
#pragma unroll 4
    for (int c4 = 0; c4 < 16; ++c4) {
        float4 cv = *(const float4*)(ctr + c4 * 4);
        const float* cvp = (const float*)&cv;
#pragma unroll
        for (int u = 0; u < 4; ++u) {
            const int c = c4 * 4 + u;
            float4 wv = *(const float4*)(sc_w + c * NC + d0);
            sc[0] = fmaf(cvp[u], wv.x, sc[0]);
            sc[1] = fmaf(cvp[u], wv.y, sc[1]);
            sc[2] = fmaf(cvp[u], wv.z, sc[2]);
            sc[3] = fmaf(cvp[u], wv.w, sc[3]);
        }
    }
    {
        float4 gg = *(const float4*)(sc_gamma + d0);
        float4 bb = *(const float4*)(sc_beta + d0);
        float4 mm = *(const float4*)(sc_mean + d0);
        float4 vv = *(const float4*)(sc_var + d0);
        const float* gp = (const float*)&gg;
        const float* bp = (const float*)&bb;
        const float* mp = (const float*)&mm;
        const float* vp = (const float*)&vv;
        float4 o;
        float* op = (float*)&o;
#pragma unroll
        for (int r = 0; r < 4; ++r) {
            float scl = gp[r] * rsqrtf(vp[r] + EPSV);
            float shf = fmaf(-mp[r], scl, bp[r]);
            op[r] = fmaxf(fmaf(sc[r], scl, shf) + fts[r], 0.f);
        }
        *(float4*)(out + (bp0 + g) * NC + d0) = o;
    }
}

extern "C" void kernel_launch(void* const* d_in, const int* in_sizes, int n_in,
                              void* d_out, int out_size, void* d_ws, size_t ws_size,
                              hipStream_t stream) {
    const float* points    = (const float*)d_in[0];
    const float* features  = (const float*)d_in[1];
    const float* w0        = (const float*)d_in[2];
    const float* w1        = (const float*)d_in[3];
    const float* w2        = (const float*)d_in[4];
    const float* gammas    = (const float*)d_in[5];
    const float* betas     = (const float*)d_in[6];
    const float* means     = (const float*)d_in[7];
    const float* variances = (const float*)d_in[8];
    const float* sc_w      = (const float*)d_in[9];
    const float* sc_gamma  = (const float*)d_in[10];
    const float* sc_beta   = (const float*)d_in[11];
    const float* sc_mean   = (const float*)d_in[12];
    const float* sc_var    = (const float*)d_in[13];
    float* out = (float*)d_out;

    int* knn_idx = (int*)d_ws;  // NBATCH*NP*KNN ints = 2 MB

    knn_kernel<<<NBATCH, 256, 0, stream>>>(points, knn_idx);
    edgeconv_kernel<<<NBATCH * (NP / 4), 64, 0, stream>>>(
        features, w0, w1, w2, gammas, betas, means, variances,
        sc_w, sc_gamma, sc_beta, sc_mean, sc_var, knn_idx, out);
}

// Round 3
// 173.109 us; speedup vs baseline: 1.9435x; 1.9435x over previous
//
#include <hip/hip_runtime.h>
#include <math.h>

#define NBATCH 128
#define NP 256
#define NC 64
#define KNN 16
#define EPSV 1e-3f

typedef __bf16 bf16_t;
typedef bf16_t bf16x8 __attribute__((ext_vector_type(8)));
typedef float f32x4 __attribute__((ext_vector_type(4)));

static __device__ __forceinline__ f32x4 mfma16(bf16x8 a, bf16x8 b, f32x4 c) {
    return __builtin_amdgcn_mfma_f32_16x16x32_bf16(a, b, c, 0, 0, 0);
}
static __device__ __forceinline__ unsigned short f2bfu(float f) {
    union { bf16_t b; unsigned short u; } cv; cv.b = (bf16_t)f; return cv.u;
}
static __device__ __forceinline__ bf16x8 pack8(float4 a, float4 b) {
    bf16x8 r;
    r[0] = (bf16_t)a.x; r[1] = (bf16_t)a.y; r[2] = (bf16_t)a.z; r[3] = (bf16_t)a.w;
    r[4] = (bf16_t)b.x; r[5] = (bf16_t)b.y; r[6] = (bf16_t)b.z; r[7] = (bf16_t)b.w;
    return r;
}
// wave-private LDS ordering fence (rule #18: asm waitcnt needs sched_barrier)
#define LDS_FENCE() do { asm volatile("s_waitcnt lgkmcnt(0)" ::: "memory"); \
                         __builtin_amdgcn_sched_barrier(0); } while (0)

// ---------------------------------------------------------------------------
// kNN (unchanged): f64 distances, exact ordering, passes with margin.
// ---------------------------------------------------------------------------
__global__ __launch_bounds__(256) void knn_kernel(const float* __restrict__ points,
                                                  int* __restrict__ idx_out) {
    const int b = blockIdx.x;
    const int t = threadIdx.x;
    __shared__ double sx[NP], sy[NP], sz[NP], sr[NP];
    const float* pb = points + (size_t)b * NP * 3;
    {
        double x = (double)pb[t * 3 + 0];
        double y = (double)pb[t * 3 + 1];
        double z = (double)pb[t * 3 + 2];
        sx[t] = x; sy[t] = y; sz[t] = z;
        sr[t] = x * x + y * y + z * z;
    }
    __syncthreads();
    const double qx = sx[t], qy = sy[t], qz = sz[t], rp = sr[t];

    double bd[KNN];
    int bi[KNN];
#pragma unroll
    for (int i = 0; i < KNN; ++i) { bd[i] = 1e300; bi[i] = 0; }

    for (int q = 0; q < NP; ++q) {
        if (q == t) continue;
        double m = qx * sx[q] + qy * sy[q] + qz * sz[q];
        double d = (rp - 2.0 * m) + sr[q];
        if (d < bd[KNN - 1]) {
#pragma unroll
            for (int i = KNN - 1; i >= 1; --i) {
                const bool wr = d < bd[i];
                const bool sh = d < bd[i - 1];
                const double nd = sh ? bd[i - 1] : d;
                const int   ni = sh ? bi[i - 1] : q;
                if (wr) { bd[i] = nd; bi[i] = ni; }
            }
            if (d < bd[0]) { bd[0] = d; bi[0] = q; }
        }
    }
    int* op = idx_out + ((size_t)b * NP + t) * KNN;
#pragma unroll
    for (int i = 0; i < KNN; ++i) op[i] = bi[i];
}

// ---------------------------------------------------------------------------
// Prep: lay out weights in MFMA B-fragment order (bf16) + fold BN params.
// B-frag (16x16x32): lane l holds B[ks*32 + (l>>4)*8 + j][t*16 + (l&15)].
// wsf regions (ushort offsets): w0f [0,8192) 16 frags; w1f [8192,12288);
// w2f [12288,16384); scwf [16384,20480). bnp: scl[192],shf[192],sscl[64],sshf[64].
// ---------------------------------------------------------------------------
__global__ __launch_bounds__(256) void prep_kernel(
    const float* __restrict__ w0, const float* __restrict__ w1,
    const float* __restrict__ w2, const float* __restrict__ sc_w,
    const float* __restrict__ gammas, const float* __restrict__ betas,
    const float* __restrict__ means, const float* __restrict__ variances,
    const float* __restrict__ sc_gamma, const float* __restrict__ sc_beta,
    const float* __restrict__ sc_mean, const float* __restrict__ sc_var,
    unsigned short* __restrict__ wsf, float* __restrict__ bnp)
{
    const int tid = blockIdx.x * 256 + threadIdx.x;
    if (tid < 20480) {
        const float* src;
        int base;
        if (tid < 8192)       { src = w0;   base = 0; }
        else if (tid < 12288) { src = w1;   base = 8192; }
        else if (tid < 16384) { src = w2;   base = 12288; }
        else                  { src = sc_w; base = 16384; }
        const int e2 = tid - base;
        const int f = e2 >> 9;
        const int r = e2 & 511;
        const int lane = r >> 3, j = r & 7;
        const int ks = f >> 2, t = f & 3;
        const int row = ks * 32 + (lane >> 4) * 8 + j;
        const int col = t * 16 + (lane & 15);
        wsf[tid] = f2bfu(src[row * 64 + col]);
    } else {
        const int e = tid - 20480;
        if (e < 192) {
            float s = gammas[e] * rsqrtf(variances[e] + EPSV);
            bnp[e] = s;
            bnp[192 + e] = betas[e] - means[e] * s;
        } else if (e < 256) {
            const int d = e - 192;
            float s = sc_gamma[d] * rsqrtf(sc_var[d] + EPSV);
            bnp[384 + d] = s;
            bnp[448 + d] = sc_beta[d] - sc_mean[d] * s;
        }
    }
}

// ---------------------------------------------------------------------------
// Edge MLP on matrix cores. One wave (64 thr) per block; wave owns 16 points.
// Per point: A = 16 neighbor rows; L1: A(16x128)=[ctr|nbr-ctr] -> 16 MFMA;
// L2/L3: 8 MFMA each via wave-private LDS slab redistribution (C->A frag).
// Shortcut: wave's 16 points form one M-tile -> 8 MFMA at start.
// Lane decomposition: i = l&15, h = l>>4. A-frag: row=i, k=h*8+j.
// C-frag: col = 16t+i, row = 4h+r.
// ---------------------------------------------------------------------------
__global__ __launch_bounds__(64, 2) void edge_kernel(
    const float* __restrict__ features, const int* __restrict__ knn_idx,
    const unsigned short* __restrict__ wsf, const float* __restrict__ bnp,
    float* __restrict__ out)
{
    __shared__ __align__(16) unsigned short slabA[16 * 72];  // row stride 144 B
    __shared__ __align__(16) unsigned short slabB[16 * 72];
    __shared__ float ftsbuf[16][64];   // [point q][channel] — FIXED: full 64 ch

    const int l = threadIdx.x;
    const int i = l & 15;
    const int h = l >> 4;
    const int p0 = blockIdx.x * 16;
    const int b = p0 >> 8;

    const bf16x8* __restrict__ W0 = (const bf16x8*)(wsf);
    const bf16x8* __restrict__ W1 = (const bf16x8*)(wsf + 8192);
    const bf16x8* __restrict__ W2 = (const bf16x8*)(wsf + 12288);
    const bf16x8* __restrict__ WS = (const bf16x8*)(wsf + 16384);

    // weights resident in registers for the whole wave lifetime
    bf16x8 w0r[4][4], w1r[2][4], w2r[2][4];
#pragma unroll
    for (int ks = 0; ks < 4; ++ks)
#pragma unroll
        for (int t = 0; t < 4; ++t) w0r[ks][t] = W0[(ks * 4 + t) * 64 + l];
#pragma unroll
    for (int ks = 0; ks < 2; ++ks)
#pragma unroll
        for (int t = 0; t < 4; ++t) {
            w1r[ks][t] = W1[(ks * 4 + t) * 64 + l];
            w2r[ks][t] = W2[(ks * 4 + t) * 64 + l];
        }

    float scl[3][4], shf[3][4], sscl[4], sshf[4];
#pragma unroll
    for (int L = 0; L < 3; ++L)
#pragma unroll
        for (int t = 0; t < 4; ++t) {
            scl[L][t] = bnp[L * 64 + t * 16 + i];
            shf[L][t] = bnp[192 + L * 64 + t * 16 + i];
        }
#pragma unroll
    for (int t = 0; t < 4; ++t) {
        sscl[t] = bnp[384 + t * 16 + i];
        sshf[t] = bnp[448 + t * 16 + i];
    }

    // ---- shortcut GEMM: rows = this wave's 16 points ----
    f32x4 scq[4];
    {
        const float* fp = features + (size_t)(p0 + i) * NC;
        float4 c0 = *(const float4*)(fp + h * 8);
        float4 c1 = *(const float4*)(fp + h * 8 + 4);
        float4 c2 = *(const float4*)(fp + 32 + h * 8);
        float4 c3 = *(const float4*)(fp + 32 + h * 8 + 4);
        bf16x8 a0 = pack8(c0, c1), a1 = pack8(c2, c3);
#pragma unroll
        for (int t = 0; t < 4; ++t) {
            f32x4 acc = {0.f, 0.f, 0.f, 0.f};
            acc = mfma16(a0, WS[(0 * 4 + t) * 64 + l], acc);
            acc = mfma16(a1, WS[(1 * 4 + t) * 64 + l], acc);
#pragma unroll
            for (int r = 0; r < 4; ++r)
                scq[t][r] = fmaf(acc[r], sscl[t], sshf[t]);  // BN'ed, pre-relu
        }
    }

    for (int q = 0; q < 16; ++q) {
        const int p = p0 + q;
        const int nk = knn_idx[p * KNN + i];           // lane's neighbor (k = i)
        const float* cp = features + (size_t)p * NC;
        const float* sp = features + (size_t)(b * NP + nk) * NC;
        float4 c0 = *(const float4*)(cp + h * 8);
        float4 c1 = *(const float4*)(cp + h * 8 + 4);
        float4 c2 = *(const float4*)(cp + 32 + h * 8);
        float4 c3 = *(const float4*)(cp + 32 + h * 8 + 4);
        float4 n0 = *(const float4*)(sp + h * 8);
        float4 n1 = *(const float4*)(sp + h * 8 + 4);
        float4 n2 = *(const float4*)(sp + 32 + h * 8);
        float4 n3 = *(const float4*)(sp + 32 + h * 8 + 4);
        float4 d0, d1, d2, d3;
        d0.x = n0.x - c0.x; d0.y = n0.y - c0.y; d0.z = n0.z - c0.z; d0.w = n0.w - c0.w;
        d1.x = n1.x - c1.x; d1.y = n1.y - c1.y; d1.z = n1.z - c1.z; d1.w = n1.w - c1.w;
        d2.x = n2.x - c2.x; d2.y = n2.y - c2.y; d2.z = n2.z - c2.z; d2.w = n2.w - c2.w;
        d3.x = n3.x - c3.x; d3.y = n3.y - c3.y; d3.z = n3.z - c3.z; d3.w = n3.w - c3.w;
        bf16x8 fA[4];
        fA[0] = pack8(c0, c1);  // A cols 0..63  = center
        fA[1] = pack8(c2, c3);
        fA[2] = pack8(d0, d1);  // A cols 64..127 = nbr - center
        fA[3] = pack8(d2, d3);

        // ---- layer 1 -> slabA ----
#pragma unroll
        for (int t = 0; t < 4; ++t) {
            f32x4 acc = {0.f, 0.f, 0.f, 0.f};
#pragma unroll
            for (int ks = 0; ks < 4; ++ks) acc = mfma16(fA[ks], w0r[ks][t], acc);
#pragma unroll
            for (int r = 0; r < 4; ++r) {
                float y = fmaxf(fmaf(acc[r], scl[0][t], shf[0][t]), 0.f);
                slabA[(h * 4 + r) * 72 + t * 16 + i] = f2bfu(y);
            }
        }
        LDS_FENCE();

        // ---- layer 2 -> slabB ----
        bf16x8 a20 = *(const bf16x8*)(slabA + i * 72 + h * 8);
        bf16x8 a21 = *(const bf16x8*)(slabA + i * 72 + h * 8 + 32);
#pragma unroll
        for (int t = 0; t < 4; ++t) {
            f32x4 acc = {0.f, 0.f, 0.f, 0.f};
            acc = mfma16(a20, w1r[0][t], acc);
            acc = mfma16(a21, w1r[1][t], acc);
#pragma unroll
            for (int r = 0; r < 4; ++r) {
                float y = fmaxf(fmaf(acc[r], scl[1][t], shf[1][t]), 0.f);
                slabB[(h * 4 + r) * 72 + t * 16 + i] = f2bfu(y);
            }
        }
        LDS_FENCE();

        // ---- layer 3 -> fts (mean over k) ----
        bf16x8 a30 = *(const bf16x8*)(slabB + i * 72 + h * 8);
        bf16x8 a31 = *(const bf16x8*)(slabB + i * 72 + h * 8 + 32);
        float fts[4];
#pragma unroll
        for (int t = 0; t < 4; ++t) {
            f32x4 acc = {0.f, 0.f, 0.f, 0.f};
            acc = mfma16(a30, w2r[0][t], acc);
            acc = mfma16(a31, w2r[1][t], acc);
            float s = 0.f;
#pragma unroll
            for (int r = 0; r < 4; ++r)
                s += fmaxf(fmaf(acc[r], scl[2][t], shf[2][t]), 0.f);
            s += __shfl_xor(s, 16, 64);  // reduce over h-groups (same i)
            s += __shfl_xor(s, 32, 64);
            fts[t] = s * (1.f / 16.f);   // now: fts of point q, channel t*16+i
        }
        if (h == 0) {                    // FIXED: 16 lanes cover all 64 channels
#pragma unroll
            for (int t = 0; t < 4; ++t) ftsbuf[q][t * 16 + i] = fts[t];
        }
        LDS_FENCE();  // covers slab WAR for next iter + ftsbuf visibility
    }

    // ---- epilogue: out = relu(sc + fts); lane covers points 4h+r, cols 16t+i
#pragma unroll
    for (int r = 0; r < 4; ++r) {
        const int q = h * 4 + r;
        float* op = out + (size_t)(p0 + q) * NC;
#pragma unroll
        for (int t = 0; t < 4; ++t)
            op[t * 16 + i] = fmaxf(scq[t][r] + ftsbuf[q][t * 16 + i], 0.f);
    }
}

extern "C" void kernel_launch(void* const* d_in, const int* in_sizes, int n_in,
                              void* d_out, int out_size, void* d_ws, size_t ws_size,
                              hipStream_t stream) {
    const float* points    = (const float*)d_in[0];
    const float* features  = (const float*)d_in[1];
    const float* w0        = (const float*)d_in[2];
    const float* w1        = (const float*)d_in[3];
    const float* w2        = (const float*)d_in[4];
    const float* gammas    = (const float*)d_in[5];
    const float* betas     = (const float*)d_in[6];
    const float* means     = (const float*)d_in[7];
    const float* variances = (const float*)d_in[8];
    const float* sc_w      = (const float*)d_in[9];
    const float* sc_gamma  = (const float*)d_in[10];
    const float* sc_beta   = (const float*)d_in[11];
    const float* sc_mean   = (const float*)d_in[12];
    const float* sc_var    = (const float*)d_in[13];
    float* out = (float*)d_out;

    int* knn_buf = (int*)d_ws;                                        // 2 MB
    unsigned short* wsf = (unsigned short*)((char*)d_ws + (1 << 21)); // 40 KB
    float* bnp = (float*)((char*)d_ws + (1 << 21) + 40960);           // 1.8 KB

    prep_kernel<<<81, 256, 0, stream>>>(w0, w1, w2, sc_w, gammas, betas, means,
                                        variances, sc_gamma, sc_beta, sc_mean,
                                        sc_var, wsf, bnp);
    knn_kernel<<<NBATCH, 256, 0, stream>>>(points, knn_buf);
    edge_kernel<<<NBATCH * NP / 16, 64, 0, stream>>>(features, knn_buf, wsf, bnp, out);
}

// Round 4
// 81.012 us; speedup vs baseline: 4.1529x; 2.1368x over previous
//
#include <hip/hip_runtime.h>
#include <math.h>

#define NBATCH 128
#define NP 256
#define NC 64
#define KNN 16
#define EPSV 1e-3f
#define INF32 3.0e38f

typedef __bf16 bf16_t;
typedef bf16_t bf16x8 __attribute__((ext_vector_type(8)));
typedef float f32x4 __attribute__((ext_vector_type(4)));

static __device__ __forceinline__ f32x4 mfma16(bf16x8 a, bf16x8 b, f32x4 c) {
    return __builtin_amdgcn_mfma_f32_16x16x32_bf16(a, b, c, 0, 0, 0);
}
static __device__ __forceinline__ unsigned short f2bfu(float f) {
    union { bf16_t b; unsigned short u; } cv; cv.b = (bf16_t)f; return cv.u;
}
static __device__ __forceinline__ bf16x8 pack8(float4 a, float4 b) {
    bf16x8 r;
    r[0] = (bf16_t)a.x; r[1] = (bf16_t)a.y; r[2] = (bf16_t)a.z; r[3] = (bf16_t)a.w;
    r[4] = (bf16_t)b.x; r[5] = (bf16_t)b.y; r[6] = (bf16_t)b.z; r[7] = (bf16_t)b.w;
    return r;
}
// wave-private LDS ordering fence (rule #18: asm waitcnt needs sched_barrier)
#define LDS_FENCE() do { asm volatile("s_waitcnt lgkmcnt(0)" ::: "memory"); \
                         __builtin_amdgcn_sched_barrier(0); } while (0)

// 16-level predicated sorted insertion, read-old semantics (levels independent).
// Strict < keeps earliest-seen on exact ties (= jax stable top_k tie order).
#define INSERT16(d_, q_)                                              \
    do {                                                              \
        _Pragma("unroll")                                             \
        for (int ii = KNN - 1; ii >= 1; --ii) {                       \
            const bool wr = (d_) < bd[ii];                            \
            const bool sh = (d_) < bd[ii - 1];                        \
            const float nd = sh ? bd[ii - 1] : (d_);                  \
            const int   ni = sh ? bi[ii - 1] : (q_);                  \
            if (wr) { bd[ii] = nd; bi[ii] = ni; }                     \
        }                                                             \
        if ((d_) < bd[0]) { bd[0] = (d_); bi[0] = (q_); }             \
    } while (0)

// ---------------------------------------------------------------------------
// kNN v2: f32 cancellation-free distances, 2-way candidate split.
// Block = 256 thr serves 128 queries of one batch-half; thread t<128 scans
// candidates [0,128) for query qbase+t, t>=128 scans [128,256) for the same
// query slot. Halves merge through LDS (partner list is sorted ascending ->
// insert with early break). Grid = 2*NBATCH -> all 256 CUs occupied.
// ---------------------------------------------------------------------------
__global__ __launch_bounds__(256) void knn_kernel(const float* __restrict__ points,
                                                  int* __restrict__ idx_out) {
    const int bb = blockIdx.x >> 1;
    const int qbase = (blockIdx.x & 1) * 128;
    const int t = threadIdx.x;
    const int qt = t & 127;
    const int half = t >> 7;
    const int p = qbase + qt;            // my query (within batch)

    __shared__ __align__(16) float4 sp[NP];
    __shared__ float sd[128][17];
    __shared__ int   si[128][17];

    const float* pb = points + (size_t)bb * NP * 3;
    sp[t] = make_float4(pb[t * 3 + 0], pb[t * 3 + 1], pb[t * 3 + 2], 0.f);
    __syncthreads();

    const float4 qp = sp[p];
    float bd[KNN];
    int bi[KNN];
#pragma unroll
    for (int i = 0; i < KNN; ++i) { bd[i] = INF32; bi[i] = 0; }

    const int cbase = half * 128;        // wave-uniform
#pragma unroll 4
    for (int c = 0; c < 128; ++c) {
        const int cand = cbase + c;
        const float4 P = sp[cand];       // wave-uniform addr -> LDS broadcast
        const float dx = qp.x - P.x, dy = qp.y - P.y, dz = qp.z - P.z;
        float d = fmaf(dx, dx, fmaf(dy, dy, dz * dz));
        d = (cand == p) ? INF32 : d;     // self-exclusion, branchless
        INSERT16(d, cand);
    }

    if (half == 1) {
#pragma unroll
        for (int i = 0; i < KNN; ++i) { sd[qt][i] = bd[i]; si[qt][i] = bi[i]; }
    }
    __syncthreads();
    if (half == 0) {
        // merge partner's sorted list; all partner indices >= 128 > mine,
        // so strict < keeps lower index on ties (jax order).
        for (int j = 0; j < KNN; ++j) {
            const float d = sd[qt][j];
            if (d >= bd[KNN - 1]) break;   // ascending -> rest can't qualify
            const int vi = si[qt][j];
            INSERT16(d, vi);
        }
        int* op = idx_out + ((size_t)bb * NP + p) * KNN;
#pragma unroll
        for (int i = 0; i < KNN; ++i) op[i] = bi[i];
    }
}

// ---------------------------------------------------------------------------
// Prep (unchanged): lay out weights in MFMA B-fragment order + fold BN params.
// B-frag (16x16x32): lane l holds B[ks*32 + (l>>4)*8 + j][t*16 + (l&15)].
// ---------------------------------------------------------------------------
__global__ __launch_bounds__(256) void prep_kernel(
    const float* __restrict__ w0, const float* __restrict__ w1,
    const float* __restrict__ w2, const float* __restrict__ sc_w,
    const float* __restrict__ gammas, const float* __restrict__ betas,
    const float* __restrict__ means, const float* __restrict__ variances,
    const float* __restrict__ sc_gamma, const float* __restrict__ sc_beta,
    const float* __restrict__ sc_mean, const float* __restrict__ sc_var,
    unsigned short* __restrict__ wsf, float* __restrict__ bnp)
{
    const int tid = blockIdx.x * 256 + threadIdx.x;
    if (tid < 20480) {
        const float* src;
        int base;
        if (tid < 8192)       { src = w0;   base = 0; }
        else if (tid < 12288) { src = w1;   base = 8192; }
        else if (tid < 16384) { src = w2;   base = 12288; }
        else                  { src = sc_w; base = 16384; }
        const int e2 = tid - base;
        const int f = e2 >> 9;
        const int r = e2 & 511;
        const int lane = r >> 3, j = r & 7;
        const int ks = f >> 2, t = f & 3;
        const int row = ks * 32 + (lane >> 4) * 8 + j;
        const int col = t * 16 + (lane & 15);
        wsf[tid] = f2bfu(src[row * 64 + col]);
    } else {
        const int e = tid - 20480;
        if (e < 192) {
            float s = gammas[e] * rsqrtf(variances[e] + EPSV);
            bnp[e] = s;
            bnp[192 + e] = betas[e] - means[e] * s;
        } else if (e < 256) {
            const int d = e - 192;
            float s = sc_gamma[d] * rsqrtf(sc_var[d] + EPSV);
            bnp[384 + d] = s;
            bnp[448 + d] = sc_beta[d] - sc_mean[d] * s;
        }
    }
}

// ---------------------------------------------------------------------------
// Edge MLP on matrix cores (unchanged from R3 — passing).
// ---------------------------------------------------------------------------
__global__ __launch_bounds__(64, 2) void edge_kernel(
    const float* __restrict__ features, const int* __restrict__ knn_idx,
    const unsigned short* __restrict__ wsf, const float* __restrict__ bnp,
    float* __restrict__ out)
{
    __shared__ __align__(16) unsigned short slabA[16 * 72];  // row stride 144 B
    __shared__ __align__(16) unsigned short slabB[16 * 72];
    __shared__ float ftsbuf[16][64];   // [point q][channel]

    const int l = threadIdx.x;
    const int i = l & 15;
    const int h = l >> 4;
    const int p0 = blockIdx.x * 16;
    const int b = p0 >> 8;

    const bf16x8* __restrict__ W0 = (const bf16x8*)(wsf);
    const bf16x8* __restrict__ W1 = (const bf16x8*)(wsf + 8192);
    const bf16x8* __restrict__ W2 = (const bf16x8*)(wsf + 12288);
    const bf16x8* __restrict__ WS = (const bf16x8*)(wsf + 16384);

    // weights resident in registers for the whole wave lifetime
    bf16x8 w0r[4][4], w1r[2][4], w2r[2][4];
#pragma unroll
    for (int ks = 0; ks < 4; ++ks)
#pragma unroll
        for (int t = 0; t < 4; ++t) w0r[ks][t] = W0[(ks * 4 + t) * 64 + l];
#pragma unroll
    for (int ks = 0; ks < 2; ++ks)
#pragma unroll
        for (int t = 0; t < 4; ++t) {
            w1r[ks][t] = W1[(ks * 4 + t) * 64 + l];
            w2r[ks][t] = W2[(ks * 4 + t) * 64 + l];
        }

    float scl[3][4], shf[3][4], sscl[4], sshf[4];
#pragma unroll
    for (int L = 0; L < 3; ++L)
#pragma unroll
        for (int t = 0; t < 4; ++t) {
            scl[L][t] = bnp[L * 64 + t * 16 + i];
            shf[L][t] = bnp[192 + L * 64 + t * 16 + i];
        }
#pragma unroll
    for (int t = 0; t < 4; ++t) {
        sscl[t] = bnp[384 + t * 16 + i];
        sshf[t] = bnp[448 + t * 16 + i];
    }

    // ---- shortcut GEMM: rows = this wave's 16 points ----
    f32x4 scq[4];
    {
        const float* fp = features + (size_t)(p0 + i) * NC;
        float4 c0 = *(const float4*)(fp + h * 8);
        float4 c1 = *(const float4*)(fp + h * 8 + 4);
        float4 c2 = *(const float4*)(fp + 32 + h * 8);
        float4 c3 = *(const float4*)(fp + 32 + h * 8 + 4);
        bf16x8 a0 = pack8(c0, c1), a1 = pack8(c2, c3);
#pragma unroll
        for (int t = 0; t < 4; ++t) {
            f32x4 acc = {0.f, 0.f, 0.f, 0.f};
            acc = mfma16(a0, WS[(0 * 4 + t) * 64 + l], acc);
            acc = mfma16(a1, WS[(1 * 4 + t) * 64 + l], acc);
#pragma unroll
            for (int r = 0; r < 4; ++r)
                scq[t][r] = fmaf(acc[r], sscl[t], sshf[t]);  // BN'ed, pre-relu
        }
    }

    for (int q = 0; q < 16; ++q) {
        const int p = p0 + q;
        const int nk = knn_idx[p * KNN + i];           // lane's neighbor (k = i)
        const float* cp = features + (size_t)p * NC;
        const float* sp = features + (size_t)(b * NP + nk) * NC;
        float4 c0 = *(const float4*)(cp + h * 8);
        float4 c1 = *(const float4*)(cp + h * 8 + 4);
        float4 c2 = *(const float4*)(cp + 32 + h * 8);
        float4 c3 = *(const float4*)(cp + 32 + h * 8 + 4);
        float4 n0 = *(const float4*)(sp + h * 8);
        float4 n1 = *(const float4*)(sp + h * 8 + 4);
        float4 n2 = *(const float4*)(sp + 32 + h * 8);
        float4 n3 = *(const float4*)(sp + 32 + h * 8 + 4);
        float4 d0, d1, d2, d3;
        d0.x = n0.x - c0.x; d0.y = n0.y - c0.y; d0.z = n0.z - c0.z; d0.w = n0.w - c0.w;
        d1.x = n1.x - c1.x; d1.y = n1.y - c1.y; d1.z = n1.z - c1.z; d1.w = n1.w - c1.w;
        d2.x = n2.x - c2.x; d2.y = n2.y - c2.y; d2.z = n2.z - c2.z; d2.w = n2.w - c2.w;
        d3.x = n3.x - c3.x; d3.y = n3.y - c3.y; d3.z = n3.z - c3.z; d3.w = n3.w - c3.w;
        bf16x8 fA[4];
        fA[0] = pack8(c0, c1);  // A cols 0..63  = center
        fA[1] = pack8(c2, c3);
        fA[2] = pack8(d0, d1);  // A cols 64..127 = nbr - center
        fA[3] = pack8(d2, d3);

        // ---- layer 1 -> slabA ----
#pragma unroll
        for (int t = 0; t < 4; ++t) {
            f32x4 acc = {0.f, 0.f, 0.f, 0.f};
#pragma unroll
            for (int ks = 0; ks < 4; ++ks) acc = mfma16(fA[ks], w0r[ks][t], acc);
#pragma unroll
            for (int r = 0; r < 4; ++r) {
                float y = fmaxf(fmaf(acc[r], scl[0][t], shf[0][t]), 0.f);
                slabA[(h * 4 + r) * 72 + t * 16 + i] = f2bfu(y);
            }
        }
        LDS_FENCE();

        // ---- layer 2 -> slabB ----
        bf16x8 a20 = *(const bf16x8*)(slabA + i * 72 + h * 8);
        bf16x8 a21 = *(const bf16x8*)(slabA + i * 72 + h * 8 + 32);
#pragma unroll
        for (int t = 0; t < 4; ++t) {
            f32x4 acc = {0.f, 0.f, 0.f, 0.f};
            acc = mfma16(a20, w1r[0][t], acc);
            acc = mfma16(a21, w1r[1][t], acc);
#pragma unroll
            for (int r = 0; r < 4; ++r) {
                float y = fmaxf(fmaf(acc[r], scl[1][t], shf[1][t]), 0.f);
                slabB[(h * 4 + r) * 72 + t * 16 + i] = f2bfu(y);
            }
        }
        LDS_FENCE();

        // ---- layer 3 -> fts (mean over k) ----
        bf16x8 a30 = *(const bf16x8*)(slabB + i * 72 + h * 8);
        bf16x8 a31 = *(const bf16x8*)(slabB + i * 72 + h * 8 + 32);
        float fts[4];
#pragma unroll
        for (int t = 0; t < 4; ++t) {
            f32x4 acc = {0.f, 0.f, 0.f, 0.f};
            acc = mfma16(a30, w2r[0][t], acc);
            acc = mfma16(a31, w2r[1][t], acc);
            float s = 0.f;
#pragma unroll
            for (int r = 0; r < 4; ++r)
                s += fmaxf(fmaf(acc[r], scl[2][t], shf[2][t]), 0.f);
            s += __shfl_xor(s, 16, 64);  // reduce over h-groups (same i)
            s += __shfl_xor(s, 32, 64);
            fts[t] = s * (1.f / 16.f);   // fts of point q, channel t*16+i
        }
        if (h == 0) {                    // 16 lanes cover all 64 channels
#pragma unroll
            for (int t = 0; t < 4; ++t) ftsbuf[q][t * 16 + i] = fts[t];
        }
        LDS_FENCE();  // covers slab WAR for next iter + ftsbuf visibility
    }

    // ---- epilogue: out = relu(sc + fts); lane covers points 4h+r, cols 16t+i
#pragma unroll
    for (int r = 0; r < 4; ++r) {
        const int q = h * 4 + r;
        float* op = out + (size_t)(p0 + q) * NC;
#pragma unroll
        for (int t = 0; t < 4; ++t)
            op[t * 16 + i] = fmaxf(scq[t][r] + ftsbuf[q][t * 16 + i], 0.f);
    }
}

extern "C" void kernel_launch(void* const* d_in, const int* in_sizes, int n_in,
                              void* d_out, int out_size, void* d_ws, size_t ws_size,
                              hipStream_t stream) {
    const float* points    = (const float*)d_in[0];
    const float* features  = (const float*)d_in[1];
    const float* w0        = (const float*)d_in[2];
    const float* w1        = (const float*)d_in[3];
    const float* w2        = (const float*)d_in[4];
    const float* gammas    = (const float*)d_in[5];
    const float* betas     = (const float*)d_in[6];
    const float* means     = (const float*)d_in[7];
    const float* variances = (const float*)d_in[8];
    const float* sc_w      = (const float*)d_in[9];
    const float* sc_gamma  = (const float*)d_in[10];
    const float* sc_beta   = (const float*)d_in[11];
    const float* sc_mean   = (const float*)d_in[12];
    const float* sc_var    = (const float*)d_in[13];
    float* out = (float*)d_out;

    int* knn_buf = (int*)d_ws;                                        // 2 MB
    unsigned short* wsf = (unsigned short*)((char*)d_ws + (1 << 21)); // 40 KB
    float* bnp = (float*)((char*)d_ws + (1 << 21) + 40960);           // 1.8 KB

    prep_kernel<<<81, 256, 0, stream>>>(w0, w1, w2, sc_w, gammas, betas, means,
                                        variances, sc_gamma, sc_beta, sc_mean,
                                        sc_var, wsf, bnp);
    knn_kernel<<<NBATCH * 2, 256, 0, stream>>>(points, knn_buf);
    edge_kernel<<<NBATCH * NP / 16, 64, 0, stream>>>(features, knn_buf, wsf, bnp, out);
}